// Round 11
// baseline (237.286 us; speedup 1.0000x reference)
//
#include <hip/hip_runtime.h>
#include <hip/hip_bf16.h>

typedef __attribute__((ext_vector_type(8))) short bf16x8;
typedef __attribute__((ext_vector_type(16))) float f32x16;
typedef __attribute__((ext_vector_type(8))) unsigned short ushort8;

typedef __attribute__((address_space(1))) void gvoid_as1;
typedef __attribute__((address_space(3))) void lvoid_as3;

__device__ __forceinline__ void gload_lds16(const void* g, void* l) {
  __builtin_amdgcn_global_load_lds((const gvoid_as1*)g, (lvoid_as3*)l, 16, 0, 0);
}

__device__ __forceinline__ unsigned short f2b(float f) {
  __hip_bfloat16 h = __float2bfloat16(f);
  return __builtin_bit_cast(unsigned short, h);
}

// ---------------- f32 -> bf16 convert, x and W in one dispatch --------------
__global__ __launch_bounds__(256) void cvt_all(const float* __restrict__ x,
                                               const float* __restrict__ W,
                                               unsigned short* __restrict__ xb,
                                               unsigned short* __restrict__ wb) {
  int i = blockIdx.x * blockDim.x + threadIdx.x;
  const float* src;
  unsigned short* dst;
  int j;
  if (i < 3145728) {            // x: 8*2048*768 f32 = 3145728 float4
    src = x; dst = xb; j = i;
  } else {                      // W: 2304*768 = 442368 float4
    src = W; dst = wb; j = i - 3145728;
    if (j >= 442368) return;
  }
  float4 v = reinterpret_cast<const float4*>(src)[j];
  ushort4 o;
  o.x = f2b(v.x); o.y = f2b(v.y); o.z = f2b(v.z); o.w = f2b(v.w);
  reinterpret_cast<ushort4*>(dst)[j] = o;
}

// ---------------- 128x128 BK=64 MFMA GEMM, 32x32x16 shape -------------------
// Same structure as round 10; only the MFMA shape (and frag/epilogue
// indexing) changed: 16 x mfma_32x32x16 per wave-Ktile instead of 32 x
// mfma_16x16x32 (4060 vs 3380 FLOP/cyc, half the issue slots).
// A/B frag: row=lane&31, k=(lane>>5)*8+j. C/D: col=lane&31,
// row=(reg&3)+8*(reg>>2)+4*(lane>>5)  [m74/m101-verified].
// EPI 0: QKV — bf16 out; +bias; cols<768 *=scale (Q); cols>=1536 -> vt^T (V)
// EPI 1: scores — bf16 out = exp(s); per-row partial sums -> Lpart[row][32]
// EPI 2: PV — f32 out = acc * Linv[row], float4 stores via LDS
template<int EPI>
__global__ __launch_bounds__(256, 4)
void gemm128(const unsigned short* __restrict__ A, int lda, long sA,
             const unsigned short* __restrict__ Bm, int ldb, long sB,
             void* __restrict__ Cv, int ldc, long sC,
             const float* __restrict__ bias, float scale,
             unsigned short* __restrict__ vt,
             float* __restrict__ Lpart, const float* __restrict__ Linv, int K) {
  __shared__ unsigned short lsAB[16384];  // A @0 (16KB), B @8192 (16KB)
  char* const lds = (char*)lsAB;
  const int tid = threadIdx.x;
  const int lane = tid & 63;
  const int wv = tid >> 6;
  const int wr = (wv >> 1) * 64;      // wave row offset (0/64)
  const int wc = (wv & 1) * 64;       // wave col offset (0/64)
  const int l31 = lane & 31;
  const int lhi = lane >> 5;          // 0/1: k-oct (operands), +4 rows (C/D)
  const int swzf = (l31 & 7) << 4;    // frag-read XOR (row&7 == l31&7)

  // 3D bijective XCD-aware swizzle over the FULL grid (z included)
  const int gx = gridDim.x;
  const int gxy = gx * gridDim.y;
  const int nwg = gxy * gridDim.z;
  const int orig = (blockIdx.z * gridDim.y + blockIdx.y) * gx + blockIdx.x;
  const int xcd = orig & 7, idx = orig >> 3;
  const int q8 = nwg >> 3, r8 = nwg & 7;
  const int wg = (xcd < r8 ? xcd * (q8 + 1) : r8 * (q8 + 1) + (xcd - r8) * q8) + idx;
  const int bz = wg / gxy;
  const int rem = wg - bz * gxy;
  const int brow = (rem / gx) * 128;
  const int bcol = (rem % gx) * 128;

  const unsigned short* Ab = A + (size_t)bz * sA;
  const unsigned short* Bb = Bm + (size_t)bz * sB;

  f32x16 acc[2][2];
#pragma unroll
  for (int mb = 0; mb < 2; mb++)
#pragma unroll
    for (int nb = 0; nb < 2; nb++)
#pragma unroll
      for (int r = 0; r < 16; r++) acc[mb][nb][r] = 0.f;

  for (int kk = 0; kk < K; kk += 64) {
    // stage 128x64 A and B tiles (unchanged from round 10)
#pragma unroll
    for (int j = 0; j < 4; j++) {
      const int s = tid + j * 256;
      const int r = s >> 3;
      const int c = ((s & 7) ^ (r & 7)) * 8;
      gload_lds16(Ab + (size_t)(brow + r) * lda + kk + c, lds + s * 16);
      gload_lds16(Bb + (size_t)(bcol + r) * ldb + kk + c, lds + 16384 + s * 16);
    }
    __syncthreads();
    // frag reads: row = base + l31, k-slot = ks*2 + lhi (16B), XOR-swizzled
    bf16x8 af[2][4], bfr[2][4];
#pragma unroll
    for (int mb = 0; mb < 2; mb++)
#pragma unroll
      for (int ks = 0; ks < 4; ks++)
        af[mb][ks] = *(const bf16x8*)(lds + (wr + mb * 32 + l31) * 128 +
                                      ((ks * 32 + lhi * 16) ^ swzf));
#pragma unroll
    for (int nb = 0; nb < 2; nb++)
#pragma unroll
      for (int ks = 0; ks < 4; ks++)
        bfr[nb][ks] = *(const bf16x8*)(lds + 16384 + (wc + nb * 32 + l31) * 128 +
                                       ((ks * 32 + lhi * 16) ^ swzf));
#pragma unroll
    for (int ks = 0; ks < 4; ks++)
#pragma unroll
      for (int mb = 0; mb < 2; mb++)
#pragma unroll
        for (int nb = 0; nb < 2; nb++)
          acc[mb][nb] = __builtin_amdgcn_mfma_f32_32x32x16_bf16(
              af[mb][ks], bfr[nb][ks], acc[mb][nb], 0, 0, 0);
    __syncthreads();
  }

  // ---- epilogue. C/D: col=l31, row=(r&3)+8*(r>>2)+4*lhi ----
  if (EPI == 2) {
    // f32 out * Linv[row]; float4 stores via LDS (two 64-row halves).
    float* C = (float*)Cv + (size_t)bz * sC;
    const float* Lb = Linv + (size_t)bz * 2048 + brow + wr + 4 * lhi;
    float4 li4[2][4];
#pragma unroll
    for (int mb = 0; mb < 2; mb++)
#pragma unroll
      for (int g = 0; g < 4; g++)
        li4[mb][g] = *(const float4*)(Lb + mb * 32 + g * 8);
    const int myh = wr >> 6;
#pragma unroll
    for (int h = 0; h < 2; ++h) {
      if (myh == h) {
#pragma unroll
        for (int mb = 0; mb < 2; mb++)
#pragma unroll
          for (int nb = 0; nb < 2; nb++)
#pragma unroll
            for (int r = 0; r < 16; r++) {
              const int R = mb * 32 + (r & 3) + 8 * (r >> 2) + 4 * lhi;  // 0..63
              const int Cc = wc + nb * 32 + l31;                          // 0..127
              *(float*)(lds + R * 512 + ((Cc * 4) ^ ((R & 7) << 4))) =
                  acc[mb][nb][r] * ((const float*)&li4[mb][r >> 2])[r & 3];
            }
      }
      __syncthreads();
      float* Ch = C + (size_t)(brow + h * 64) * ldc + bcol;
#pragma unroll
      for (int i = 0; i < 8; i++) {
        const int id = tid + i * 256;
        const int row = id >> 5, sl = id & 31;
        float4 vv = *(const float4*)(lds + row * 512 +
                                     ((sl * 16) ^ ((row & 7) << 4)));
        *(float4*)(Ch + (size_t)row * ldc + sl * 4) = vv;
      }
      __syncthreads();
    }
  } else {
    // bf16 path: round-trip through LDS for ushort8 stores.
    const bool isV = (EPI == 0) && (bcol >= 1536);
    const bool isQ = (EPI == 0) && (bcol < 768);
    float bv[2];
    if (EPI == 0) {
#pragma unroll
      for (int nb = 0; nb < 2; nb++) bv[nb] = bias[bcol + wc + nb * 32 + l31];
    }
    float rs[2][16];  // per-(mb,reg) row partial sums (EPI 1)
    if (EPI == 1) {
#pragma unroll
      for (int mb = 0; mb < 2; mb++)
#pragma unroll
        for (int r = 0; r < 16; r++) rs[mb][r] = 0.f;
    }
#pragma unroll
    for (int mb = 0; mb < 2; mb++)
#pragma unroll
      for (int nb = 0; nb < 2; nb++)
#pragma unroll
        for (int r = 0; r < 16; r++) {
          float v = acc[mb][nb][r];
          if (EPI == 0) {
            v += bv[nb];
            if (isQ) v *= scale;
          }
          if (EPI == 1) {
            v = exp2f(v * 1.4426950408889634f);  // exp(s), no max needed
            rs[mb][r] += v;
          }
          const int R = wr + mb * 32 + (r & 3) + 8 * (r >> 2) + 4 * lhi;
          const int Cc = wc + nb * 32 + l31;
          const int row_ = isV ? Cc : R;
          const int col_ = isV ? R : Cc;
          *(unsigned short*)(lds + row_ * 256 +
                             ((col_ * 2) ^ ((row_ & 15) << 4))) = f2b(v);
        }
    if (EPI == 1) {
      // reduce across the 32 col-lanes of this wave's two 32-col blocks
#pragma unroll
      for (int mb = 0; mb < 2; mb++)
#pragma unroll
        for (int r = 0; r < 16; r++) {
          float s = rs[mb][r];
          s += __shfl_xor(s, 1);
          s += __shfl_xor(s, 2);
          s += __shfl_xor(s, 4);
          s += __shfl_xor(s, 8);
          s += __shfl_xor(s, 16);
          rs[mb][r] = s;
        }
      if (l31 == 0) {  // lanes 0 and 32 write rows +0 / +4
        const int rbase = brow + wr + 4 * lhi;
        const int slot = (bcol >> 7) * 2 + (wv & 1);
#pragma unroll
        for (int mb = 0; mb < 2; mb++)
#pragma unroll
          for (int r = 0; r < 16; r++) {
            const int row = rbase + mb * 32 + (r & 3) + 8 * (r >> 2);
            Lpart[((size_t)bz * 2048 + row) * 32 + slot] = rs[mb][r];
          }
      }
    }
    __syncthreads();
    // read back rows, 16B chunks (unchanged)
    if (isV) {
      const int b = brow >> 11;
      const int l0 = brow & 2047;
      const int e0 = bcol - 1536;
      unsigned short* dst = vt + ((size_t)b * 768 + e0) * 2048 + l0;
#pragma unroll
      for (int i = 0; i < 8; i++) {
        const int id = tid + i * 256;
        const int row = id >> 4, sl = id & 15;
        ushort8 vv = *(const ushort8*)(lds + row * 256 +
                                       ((sl * 16) ^ ((row & 15) << 4)));
        *(ushort8*)(dst + (size_t)row * 2048 + sl * 8) = vv;
      }
    } else {
      unsigned short* C = (unsigned short*)Cv + (size_t)bz * sC +
                          (size_t)brow * ldc + bcol;
#pragma unroll
      for (int i = 0; i < 8; i++) {
        const int id = tid + i * 256;
        const int row = id >> 4, sl = id & 15;
        ushort8 vv = *(const ushort8*)(lds + row * 256 +
                                       ((sl * 16) ^ ((row & 15) << 4)));
        *(ushort8*)(C + (size_t)row * ldc + sl * 8) = vv;
      }
    }
  }
}

// ---------------- Lpart[rows][32] -> Linv[rows] = 1/sum ---------------------
__global__ __launch_bounds__(256) void sum_l(const float* __restrict__ Lpart,
                                             float* __restrict__ Linv, int nrows) {
  int r = blockIdx.x * blockDim.x + threadIdx.x;
  if (r >= nrows) return;
  const float4* p = (const float4*)(Lpart + (size_t)r * 32);
  float s = 0.f;
#pragma unroll
  for (int i = 0; i < 8; i++) {
    float4 v = p[i];
    s += (v.x + v.y) + (v.z + v.w);
  }
  Linv[r] = 1.0f / s;
}

// ---------------- host ------------------------------------------------------
extern "C" void kernel_launch(void* const* d_in, const int* in_sizes, int n_in,
                              void* d_out, int out_size, void* d_ws, size_t ws_size,
                              hipStream_t stream) {
  const float* x = (const float*)d_in[0];
  const float* W = (const float*)d_in[1];
  const float* bias = (const float*)d_in[2];
  float* out = (float*)d_out;
  char* ws = (char*)d_ws;

  unsigned short* xb = (unsigned short*)(ws);
  unsigned short* wb = (unsigned short*)(ws + 25165824);
  unsigned short* qkv = (unsigned short*)(ws + 28704768);
  unsigned short* vt = (unsigned short*)(ws + 104202240);
  unsigned short* S = (unsigned short*)(ws + 129368064);
  // Lpart/Linv reuse the xb region (xb is dead after the QKV GEMM):
  float* Lpart = (float*)(ws);                 // 16384*32*4 = 2 MB
  float* Linv = (float*)(ws + 2097152);        // 16384*4 = 64 KB
  const float scale = 0.03608439182435161f;    // 768^-0.5

  cvt_all<<<14016, 256, 0, stream>>>(x, W, xb, wb);
  // QKV = x @ W^T + b : M=16384 N=2304 K=768; Q scaled; V written to vt^T
  gemm128<0><<<dim3(18, 128, 1), 256, 0, stream>>>(
      xb, 768, 0, wb, 768, 0, qkv, 2304, 0, bias, scale, vt,
      nullptr, nullptr, 768);

  bool batched = ws_size >= (129368064UL + 67108864UL);
  if (batched) {
    // P~ = exp(Q @ K^T) per batch (scale folded into Q): M=N=2048 K=768
    gemm128<1><<<dim3(16, 16, 8), 256, 0, stream>>>(
        qkv, 2304, 2048L * 2304, qkv + 768, 2304, 2048L * 2304,
        S, 2048, 2048L * 2048, nullptr, 1.f, nullptr, Lpart, nullptr, 768);
    sum_l<<<64, 256, 0, stream>>>(Lpart, Linv, 16384);
    // out = (P~ @ V) * (1/l) : M=2048 N=768 K=2048
    gemm128<2><<<dim3(6, 16, 8), 256, 0, stream>>>(
        S, 2048, 2048L * 2048, vt, 2048, 768L * 2048,
        out, 768, 2048L * 768, nullptr, 1.f, nullptr, nullptr, Linv, 2048);
  } else {
    for (int b = 0; b < 8; b++) {
      const unsigned short* qb = qkv + (size_t)b * 2048 * 2304;
      gemm128<1><<<dim3(16, 16, 1), 256, 0, stream>>>(
          qb, 2304, 0, qb + 768, 2304, 0, S, 2048, 0, nullptr, 1.f, nullptr,
          Lpart, nullptr, 768);
      sum_l<<<8, 256, 0, stream>>>(Lpart, Linv, 2048);
      gemm128<2><<<dim3(6, 16, 1), 256, 0, stream>>>(
          S, 2048, 0, vt + (size_t)b * 768 * 2048, 2048, 0,
          out + (size_t)b * 2048 * 768, 768, 0, nullptr, 1.f, nullptr,
          nullptr, Linv, 2048);
    }
  }
}

// Round 12
// 206.059 us; speedup vs baseline: 1.1515x; 1.1515x over previous
//
#include <hip/hip_runtime.h>
#include <hip/hip_bf16.h>

typedef __attribute__((ext_vector_type(8))) short bf16x8;
typedef __attribute__((ext_vector_type(4))) float f32x4;
typedef __attribute__((ext_vector_type(8))) unsigned short ushort8;

typedef __attribute__((address_space(1))) void gvoid_as1;
typedef __attribute__((address_space(3))) void lvoid_as3;

__device__ __forceinline__ void gload_lds16(const void* g, void* l) {
  __builtin_amdgcn_global_load_lds((const gvoid_as1*)g, (lvoid_as3*)l, 16, 0, 0);
}

__device__ __forceinline__ unsigned short f2b(float f) {
  __hip_bfloat16 h = __float2bfloat16(f);
  return __builtin_bit_cast(unsigned short, h);
}

// ---------------- f32 -> bf16 convert, x and W in one dispatch --------------
__global__ __launch_bounds__(256) void cvt_all(const float* __restrict__ x,
                                               const float* __restrict__ W,
                                               unsigned short* __restrict__ xb,
                                               unsigned short* __restrict__ wb) {
  int i = blockIdx.x * blockDim.x + threadIdx.x;
  const float* src;
  unsigned short* dst;
  int j;
  if (i < 3145728) {            // x: 8*2048*768 f32 = 3145728 float4
    src = x; dst = xb; j = i;
  } else {                      // W: 2304*768 = 442368 float4
    src = W; dst = wb; j = i - 3145728;
    if (j >= 442368) return;
  }
  float4 v = reinterpret_cast<const float4*>(src)[j];
  ushort4 o;
  o.x = f2b(v.x); o.y = f2b(v.y); o.z = f2b(v.z); o.w = f2b(v.w);
  reinterpret_cast<ushort4*>(dst)[j] = o;
}

// ------- 256x128 BK=64 GEMM, 8 waves x 64x64 (QKV / scores) -----------------
// Same wave-tile/swizzle/inner-loop as the proven 128^2 kernel; block tile
// 2x taller -> staging 11.7 B/KFLOP (-25%), LDS 48KB -> up to 3 blocks/CU
// with 8 waves each (16-24 waves/CU vs ~11).
// EPI 0: QKV — bf16 out; +bias; cols<768 *=scale (Q); cols>=1536 -> vt^T (V)
// EPI 1: scores — bf16 out = exp(s); per-row partial sums -> Lpart[row][32]
template<int EPI>
__global__ __launch_bounds__(512, 4)
void gemmBig(const unsigned short* __restrict__ A, int lda, long sA,
             const unsigned short* __restrict__ Bm, int ldb, long sB,
             void* __restrict__ Cv, int ldc, long sC,
             const float* __restrict__ bias, float scale,
             unsigned short* __restrict__ vt,
             float* __restrict__ Lpart, int K) {
  __shared__ char lds[49152];   // A [256x64] @0 (32KB), B [128x64] @32768
  const int tid = threadIdx.x;  // 0..511
  const int lane = tid & 63;
  const int wv = tid >> 6;            // 0..7
  const int wrow = (wv >> 1) * 64;    // 0/64/128/192
  const int wcol = (wv & 1) * 64;     // 0/64
  const int lr = lane & 15;
  const int lkb = (lane >> 4) * 16;   // 16B k-oct within 64B k-slice
  const int swz = (lane & 7) << 4;    // read-side XOR (row&7 == lr&7)

  // 3D bijective XCD-aware swizzle over the FULL grid (z included)
  const int gx = gridDim.x;
  const int gxy = gx * gridDim.y;
  const int nwg = gxy * gridDim.z;
  const int orig = (blockIdx.z * gridDim.y + blockIdx.y) * gx + blockIdx.x;
  const int xcd = orig & 7, idx = orig >> 3;
  const int q8 = nwg >> 3, r8 = nwg & 7;
  const int wg = (xcd < r8 ? xcd * (q8 + 1) : r8 * (q8 + 1) + (xcd - r8) * q8) + idx;
  const int bz = wg / gxy;
  const int rem = wg - bz * gxy;
  const int brow = (rem / gx) * 256;
  const int bcol = (rem % gx) * 128;

  const unsigned short* Ab = A + (size_t)bz * sA;
  const unsigned short* Bb = Bm + (size_t)bz * sB;

  f32x4 acc[4][4];
#pragma unroll
  for (int m = 0; m < 4; m++)
#pragma unroll
    for (int n = 0; n < 4; n++) acc[m][n] = (f32x4){0.f, 0.f, 0.f, 0.f};

  for (int kk = 0; kk < K; kk += 64) {
    // A: 2048 16B segs (4/thread); B: 1024 segs (2/thread); pre-swizzled src.
#pragma unroll
    for (int j = 0; j < 4; j++) {
      const int s = tid + j * 512;
      const int r = s >> 3;
      const int c = ((s & 7) ^ (r & 7)) * 8;
      gload_lds16(Ab + (size_t)(brow + r) * lda + kk + c, lds + s * 16);
    }
#pragma unroll
    for (int j = 0; j < 2; j++) {
      const int s = tid + j * 512;
      const int r = s >> 3;
      const int c = ((s & 7) ^ (r & 7)) * 8;
      gload_lds16(Bb + (size_t)(bcol + r) * ldb + kk + c, lds + 32768 + s * 16);
    }
    __syncthreads();
    bf16x8 af[4][2], bfr[4][2];
#pragma unroll
    for (int m = 0; m < 4; m++)
#pragma unroll
      for (int ks = 0; ks < 2; ks++)
        af[m][ks] = *(const bf16x8*)(lds + (wrow + m * 16 + lr) * 128 +
                                     ((ks * 64 + lkb) ^ swz));
#pragma unroll
    for (int n = 0; n < 4; n++)
#pragma unroll
      for (int ks = 0; ks < 2; ks++)
        bfr[n][ks] = *(const bf16x8*)(lds + 32768 + (wcol + n * 16 + lr) * 128 +
                                      ((ks * 64 + lkb) ^ swz));
#pragma unroll
    for (int m = 0; m < 4; m++)
#pragma unroll
      for (int n = 0; n < 4; n++) {
        acc[m][n] = __builtin_amdgcn_mfma_f32_16x16x32_bf16(af[m][0], bfr[n][0], acc[m][n], 0, 0, 0);
        acc[m][n] = __builtin_amdgcn_mfma_f32_16x16x32_bf16(af[m][1], bfr[n][1], acc[m][n], 0, 0, 0);
      }
    __syncthreads();
  }

  // ---- epilogue: two 128-row halves via 32KB LDS tile.
  // C/D frag layout: col=lane&15, row=(lane>>4)*4+reg
  const bool isV = (EPI == 0) && (bcol >= 1536);
  const bool isQ = (EPI == 0) && (bcol < 768);
  float bv[4];
  if (EPI == 0) {
#pragma unroll
    for (int n = 0; n < 4; n++) bv[n] = bias[bcol + wcol + n * 16 + lr];
  }
  float rs[4][4];
  if (EPI == 1) {
#pragma unroll
    for (int m = 0; m < 4; m++)
#pragma unroll
      for (int j = 0; j < 4; j++) rs[m][j] = 0.f;
  }
  const int myh = wrow >> 7;  // waves 0-3 -> half 0; 4-7 -> half 1
#pragma unroll
  for (int h = 0; h < 2; ++h) {
    if (myh == h) {
#pragma unroll
      for (int m = 0; m < 4; m++)
#pragma unroll
        for (int n = 0; n < 4; n++)
#pragma unroll
          for (int j = 0; j < 4; j++) {
            float v = acc[m][n][j];
            if (EPI == 0) {
              v += bv[n];
              if (isQ) v *= scale;
            }
            if (EPI == 1) {
              v = exp2f(v * 1.4426950408889634f);  // exp(s), no max needed
              rs[m][j] += v;
            }
            const int Rl = (wrow & 64) + m * 16 + (lane >> 4) * 4 + j;  // 0..127
            const int Cc = wcol + n * 16 + lr;                          // 0..127
            const int row_ = isV ? Cc : Rl;
            const int col_ = isV ? Rl : Cc;
            *(unsigned short*)(lds + row_ * 256 +
                               ((col_ * 2) ^ ((row_ & 15) << 4))) = f2b(v);
          }
    }
    __syncthreads();
    // write back 128x128 bf16 half: 2048 16B chunks / 512 threads = 4 iters
    if (isV) {
      const int b = brow >> 11;
      const int l0 = (brow & 2047) + h * 128;
      const int e0 = bcol - 1536;
      unsigned short* dst = vt + ((size_t)b * 768 + e0) * 2048 + l0;
#pragma unroll
      for (int i = 0; i < 4; i++) {
        const int id = tid + i * 512;
        const int row = id >> 4, sl = id & 15;
        ushort8 vv = *(const ushort8*)(lds + row * 256 +
                                       ((sl * 16) ^ ((row & 15) << 4)));
        *(ushort8*)(dst + (size_t)row * 2048 + sl * 8) = vv;
      }
    } else {
      unsigned short* C = (unsigned short*)Cv + (size_t)bz * sC +
                          (size_t)(brow + h * 128) * ldc + bcol;
#pragma unroll
      for (int i = 0; i < 4; i++) {
        const int id = tid + i * 512;
        const int row = id >> 4, sl = id & 15;
        ushort8 vv = *(const ushort8*)(lds + row * 256 +
                                       ((sl * 16) ^ ((row & 15) << 4)));
        *(ushort8*)(C + (size_t)row * ldc + sl * 8) = vv;
      }
    }
    __syncthreads();
  }
  if (EPI == 1) {
    // reduce rs across the 16 col-lanes, then one store per row-slot
#pragma unroll
    for (int m = 0; m < 4; m++)
#pragma unroll
      for (int j = 0; j < 4; j++) {
        float s = rs[m][j];
        s += __shfl_xor(s, 1);
        s += __shfl_xor(s, 2);
        s += __shfl_xor(s, 4);
        s += __shfl_xor(s, 8);
        rs[m][j] = s;
      }
    if (lr == 0) {
      float* Lp = Lpart + ((size_t)bz * 2048 + brow + wrow +
                           (lane >> 4) * 4) * 32 + (bcol >> 7) * 2 + (wv & 1);
#pragma unroll
      for (int m = 0; m < 4; m++)
#pragma unroll
        for (int j = 0; j < 4; j++) Lp[(size_t)(m * 16 + j) * 32] = rs[m][j];
    }
  }
}

// ---------------- 128x128 BK=64 GEMM (round-10, PV only) --------------------
__global__ __launch_bounds__(256, 4)
void gemmPV(const unsigned short* __restrict__ A, int lda, long sA,
            const unsigned short* __restrict__ Bm, int ldb, long sB,
            float* __restrict__ Cv, int ldc, long sC,
            const float* __restrict__ Linv, int K) {
  __shared__ unsigned short lsAB[16384];
  char* const lds = (char*)lsAB;
  const int tid = threadIdx.x;
  const int lane = tid & 63;
  const int wv = tid >> 6;
  const int wr = (wv >> 1) * 64;
  const int wc = (wv & 1) * 64;
  const int lr = lane & 15;
  const int lkb = (lane >> 4) * 16;
  const int swz = (lane & 7) << 4;

  const int gx = gridDim.x;
  const int gxy = gx * gridDim.y;
  const int nwg = gxy * gridDim.z;
  const int orig = (blockIdx.z * gridDim.y + blockIdx.y) * gx + blockIdx.x;
  const int xcd = orig & 7, idx = orig >> 3;
  const int q8 = nwg >> 3, r8 = nwg & 7;
  const int wg = (xcd < r8 ? xcd * (q8 + 1) : r8 * (q8 + 1) + (xcd - r8) * q8) + idx;
  const int bz = wg / gxy;
  const int rem = wg - bz * gxy;
  const int brow = (rem / gx) * 128;
  const int bcol = (rem % gx) * 128;

  const unsigned short* Ab = A + (size_t)bz * sA;
  const unsigned short* Bb = Bm + (size_t)bz * sB;

  f32x4 acc[4][4];
#pragma unroll
  for (int m = 0; m < 4; m++)
#pragma unroll
    for (int n = 0; n < 4; n++) acc[m][n] = (f32x4){0.f, 0.f, 0.f, 0.f};

  for (int kk = 0; kk < K; kk += 64) {
#pragma unroll
    for (int j = 0; j < 4; j++) {
      const int s = tid + j * 256;
      const int r = s >> 3;
      const int c = ((s & 7) ^ (r & 7)) * 8;
      gload_lds16(Ab + (size_t)(brow + r) * lda + kk + c, lds + s * 16);
      gload_lds16(Bb + (size_t)(bcol + r) * ldb + kk + c, lds + 16384 + s * 16);
    }
    __syncthreads();
    bf16x8 af[4][2], bfr[4][2];
#pragma unroll
    for (int m = 0; m < 4; m++)
#pragma unroll
      for (int ks = 0; ks < 2; ks++)
        af[m][ks] = *(const bf16x8*)(lds + (wr + m * 16 + lr) * 128 +
                                     ((ks * 64 + lkb) ^ swz));
#pragma unroll
    for (int n = 0; n < 4; n++)
#pragma unroll
      for (int ks = 0; ks < 2; ks++)
        bfr[n][ks] = *(const bf16x8*)(lds + 16384 + (wc + n * 16 + lr) * 128 +
                                      ((ks * 64 + lkb) ^ swz));
#pragma unroll
    for (int m = 0; m < 4; m++)
#pragma unroll
      for (int n = 0; n < 4; n++) {
        acc[m][n] = __builtin_amdgcn_mfma_f32_16x16x32_bf16(af[m][0], bfr[n][0], acc[m][n], 0, 0, 0);
        acc[m][n] = __builtin_amdgcn_mfma_f32_16x16x32_bf16(af[m][1], bfr[n][1], acc[m][n], 0, 0, 0);
      }
    __syncthreads();
  }

  // f32 out * Linv[row]; float4 stores via LDS (two 64-row halves, 32KB).
  float* C = Cv + (size_t)bz * sC;
  const int r0e = brow + wr + (lane >> 4) * 4;
  const float* Lb = Linv + (size_t)bz * 2048;
  float li[4][4];
#pragma unroll
  for (int m = 0; m < 4; m++)
#pragma unroll
    for (int j = 0; j < 4; j++) li[m][j] = Lb[r0e + m * 16 + j];
  const int myh = wr >> 6;
#pragma unroll
  for (int h = 0; h < 2; ++h) {
    if (myh == h) {
#pragma unroll
      for (int m = 0; m < 4; m++)
#pragma unroll
        for (int n = 0; n < 4; n++)
#pragma unroll
          for (int j = 0; j < 4; j++) {
            const int R = (wr & 63) + m * 16 + (lane >> 4) * 4 + j;  // 0..63
            const int Cc = wc + n * 16 + lr;                         // 0..127
            *(float*)(lds + R * 512 + ((Cc * 4) ^ ((R & 7) << 4))) =
                acc[m][n][j] * li[m][j];
          }
    }
    __syncthreads();
    float* Ch = C + (size_t)(brow + h * 64) * ldc + bcol;
#pragma unroll
    for (int i = 0; i < 8; i++) {
      const int id = tid + i * 256;
      const int row = id >> 5, sl = id & 31;
      float4 vv = *(const float4*)(lds + row * 512 +
                                   ((sl * 16) ^ ((row & 7) << 4)));
      *(float4*)(Ch + (size_t)row * ldc + sl * 4) = vv;
    }
    __syncthreads();
  }
}

// ---------------- Lpart[rows][32] -> Linv[rows] = 1/sum ---------------------
__global__ __launch_bounds__(256) void sum_l(const float* __restrict__ Lpart,
                                             float* __restrict__ Linv, int nrows) {
  int r = blockIdx.x * blockDim.x + threadIdx.x;
  if (r >= nrows) return;
  const float4* p = (const float4*)(Lpart + (size_t)r * 32);
  float s = 0.f;
#pragma unroll
  for (int i = 0; i < 8; i++) {
    float4 v = p[i];
    s += (v.x + v.y) + (v.z + v.w);
  }
  Linv[r] = 1.0f / s;
}

// ---------------- host ------------------------------------------------------
extern "C" void kernel_launch(void* const* d_in, const int* in_sizes, int n_in,
                              void* d_out, int out_size, void* d_ws, size_t ws_size,
                              hipStream_t stream) {
  const float* x = (const float*)d_in[0];
  const float* W = (const float*)d_in[1];
  const float* bias = (const float*)d_in[2];
  float* out = (float*)d_out;
  char* ws = (char*)d_ws;

  unsigned short* xb = (unsigned short*)(ws);
  unsigned short* wb = (unsigned short*)(ws + 25165824);
  unsigned short* qkv = (unsigned short*)(ws + 28704768);
  unsigned short* vt = (unsigned short*)(ws + 104202240);
  unsigned short* S = (unsigned short*)(ws + 129368064);
  // Lpart/Linv reuse the xb region (xb is dead after the QKV GEMM):
  float* Lpart = (float*)(ws);                 // 16384*32*4 = 2 MB
  float* Linv = (float*)(ws + 2097152);        // 16384*4 = 64 KB
  const float scale = 0.03608439182435161f;    // 768^-0.5

  cvt_all<<<14016, 256, 0, stream>>>(x, W, xb, wb);
  // QKV = x @ W^T + b : M=16384 N=2304 K=768; Q scaled; V written to vt^T
  gemmBig<0><<<dim3(18, 64, 1), 512, 0, stream>>>(
      xb, 768, 0, wb, 768, 0, qkv, 2304, 0, bias, scale, vt, nullptr, 768);

  bool batched = ws_size >= (129368064UL + 67108864UL);
  if (batched) {
    // P~ = exp(Q @ K^T) per batch (scale folded into Q): M=N=2048 K=768
    gemmBig<1><<<dim3(16, 8, 8), 512, 0, stream>>>(
        qkv, 2304, 2048L * 2304, qkv + 768, 2304, 2048L * 2304,
        S, 2048, 2048L * 2048, nullptr, 1.f, nullptr, Lpart, 768);
    sum_l<<<64, 256, 0, stream>>>(Lpart, Linv, 16384);
    // out = (P~ @ V) * (1/l) : M=2048 N=768 K=2048
    gemmPV<<<dim3(6, 16, 8), 256, 0, stream>>>(
        S, 2048, 2048L * 2048, vt, 2048, 768L * 2048,
        out, 768, 2048L * 768, Linv, 2048);
  } else {
    for (int b = 0; b < 8; b++) {
      const unsigned short* qb = qkv + (size_t)b * 2048 * 2304;
      gemmBig<1><<<dim3(16, 8, 1), 512, 0, stream>>>(
          qb, 2304, 0, qb + 768, 2304, 0, S, 2048, 0, nullptr, 1.f, nullptr,
          Lpart, 768);
      sum_l<<<8, 256, 0, stream>>>(Lpart, Linv, 2048);
      gemmPV<<<dim3(6, 16, 1), 256, 0, stream>>>(
          S, 2048, 0, vt + (size_t)b * 768 * 2048, 2048, 0,
          out + (size_t)b * 2048 * 768, 768, 0, Linv, 2048);
    }
  }
}

// Round 13
// 200.737 us; speedup vs baseline: 1.1821x; 1.0265x over previous
//
#include <hip/hip_runtime.h>
#include <hip/hip_bf16.h>

typedef __attribute__((ext_vector_type(8))) short bf16x8;
typedef __attribute__((ext_vector_type(4))) float f32x4;
typedef __attribute__((ext_vector_type(8))) unsigned short ushort8;

typedef __attribute__((address_space(1))) void gvoid_as1;
typedef __attribute__((address_space(3))) void lvoid_as3;

__device__ __forceinline__ void gload_lds16(const void* g, void* l) {
  __builtin_amdgcn_global_load_lds((const gvoid_as1*)g, (lvoid_as3*)l, 16, 0, 0);
}

__device__ __forceinline__ unsigned short f2b(float f) {
  __hip_bfloat16 h = __float2bfloat16(f);
  return __builtin_bit_cast(unsigned short, h);
}

// ---------------- f32 -> bf16 convert, x and W in one dispatch --------------
__global__ __launch_bounds__(256) void cvt_all(const float* __restrict__ x,
                                               const float* __restrict__ W,
                                               unsigned short* __restrict__ xb,
                                               unsigned short* __restrict__ wb) {
  int i = blockIdx.x * blockDim.x + threadIdx.x;
  const float* src;
  unsigned short* dst;
  int j;
  if (i < 3145728) {            // x: 8*2048*768 f32 = 3145728 float4
    src = x; dst = xb; j = i;
  } else {                      // W: 2304*768 = 442368 float4
    src = W; dst = wb; j = i - 3145728;
    if (j >= 442368) return;
  }
  float4 v = reinterpret_cast<const float4*>(src)[j];
  ushort4 o;
  o.x = f2b(v.x); o.y = f2b(v.y); o.z = f2b(v.z); o.w = f2b(v.w);
  reinterpret_cast<ushort4*>(dst)[j] = o;
}

// ---------------- 128x128 BK=64 MFMA GEMM (round-10 winner) -----------------
// C[m,n] = sum_k A[m,k]*B[n,k]  (both operands K-contiguous rows)
// EPI 0: QKV — bf16 out; +bias; cols<768 *=scale (Q); cols>=1536 -> vt^T (V)
// EPI 1: scores — bf16 out = exp(s); per-row partial sums -> Lpart[row][32]
// EPI 2: PV — f32 out = acc * Linv[row], float4 stores via LDS
// LDS 32KB; T2 both-sides XOR swizzle; 3D-bijective XCD swizzle (one batch
// z-slice per XCD for QK^T/PV -> K/V panels stay L2-resident).
template<int EPI>
__global__ __launch_bounds__(256, 4)
void gemm128(const unsigned short* __restrict__ A, int lda, long sA,
             const unsigned short* __restrict__ Bm, int ldb, long sB,
             void* __restrict__ Cv, int ldc, long sC,
             const float* __restrict__ bias, float scale,
             unsigned short* __restrict__ vt,
             float* __restrict__ Lpart, const float* __restrict__ Linv, int K) {
  __shared__ unsigned short lsAB[16384];  // A @0 (16KB), B @8192 (16KB)
  char* const lds = (char*)lsAB;
  const int tid = threadIdx.x;
  const int lane = tid & 63;
  const int wv = tid >> 6;
  const int wr = (wv >> 1) * 64;
  const int wc = (wv & 1) * 64;
  const int lr = lane & 15;
  const int lkb = (lane >> 4) * 16;   // 16B k-oct within 64B k-slice
  const int swz = (lane & 7) << 4;    // read-side XOR (row&7 == lr&7)

  // 3D bijective XCD-aware swizzle over the FULL grid (z included):
  // each XCD gets a contiguous chunk of (z,y,x)-linear block ids.
  const int gx = gridDim.x;
  const int gxy = gx * gridDim.y;
  const int nwg = gxy * gridDim.z;
  const int orig = (blockIdx.z * gridDim.y + blockIdx.y) * gx + blockIdx.x;
  const int xcd = orig & 7, idx = orig >> 3;
  const int q8 = nwg >> 3, r8 = nwg & 7;
  const int wg = (xcd < r8 ? xcd * (q8 + 1) : r8 * (q8 + 1) + (xcd - r8) * q8) + idx;
  const int bz = wg / gxy;
  const int rem = wg - bz * gxy;
  const int brow = (rem / gx) * 128;
  const int bcol = (rem % gx) * 128;

  const unsigned short* Ab = A + (size_t)bz * sA;
  const unsigned short* Bb = Bm + (size_t)bz * sB;

  f32x4 acc[4][4];
#pragma unroll
  for (int m = 0; m < 4; m++)
#pragma unroll
    for (int n = 0; n < 4; n++) acc[m][n] = (f32x4){0.f, 0.f, 0.f, 0.f};

  for (int kk = 0; kk < K; kk += 64) {
    // stage 128x64 A and B tiles: 1024 16B segs each, 4 per thread per op.
    // seg s -> row r=s>>3, pre-swizzled global col ((s&7)^(r&7))*8; LDS linear.
#pragma unroll
    for (int j = 0; j < 4; j++) {
      const int s = tid + j * 256;
      const int r = s >> 3;
      const int c = ((s & 7) ^ (r & 7)) * 8;
      gload_lds16(Ab + (size_t)(brow + r) * lda + kk + c, lds + s * 16);
      gload_lds16(Bb + (size_t)(bcol + r) * ldb + kk + c, lds + 16384 + s * 16);
    }
    __syncthreads();  // drains vmcnt; cross-block overlap hides the stall
    bf16x8 af[4][2], bfr[4][2];
#pragma unroll
    for (int m = 0; m < 4; m++)
#pragma unroll
      for (int ks = 0; ks < 2; ks++)
        af[m][ks] = *(const bf16x8*)(lds + (wr + m * 16 + lr) * 128 +
                                     ((ks * 64 + lkb) ^ swz));
#pragma unroll
    for (int n = 0; n < 4; n++)
#pragma unroll
      for (int ks = 0; ks < 2; ks++)
        bfr[n][ks] = *(const bf16x8*)(lds + 16384 + (wc + n * 16 + lr) * 128 +
                                      ((ks * 64 + lkb) ^ swz));
#pragma unroll
    for (int m = 0; m < 4; m++)
#pragma unroll
      for (int n = 0; n < 4; n++) {
        acc[m][n] = __builtin_amdgcn_mfma_f32_16x16x32_bf16(af[m][0], bfr[n][0], acc[m][n], 0, 0, 0);
        acc[m][n] = __builtin_amdgcn_mfma_f32_16x16x32_bf16(af[m][1], bfr[n][1], acc[m][n], 0, 0, 0);
      }
    __syncthreads();  // protect LDS before next-iter staging
  }

  // ---- epilogue. C/D frag layout: col=lane&15, row=(lane>>4)*4+reg ----
  if (EPI == 2) {
    // f32 out * Linv[row]; float4 stores via LDS (two 64-row halves, 32KB).
    float* C = (float*)Cv + (size_t)bz * sC;
    const int r0e = brow + wr + (lane >> 4) * 4;
    const float* Lb = Linv + (size_t)bz * 2048;
    float li[4][4];
#pragma unroll
    for (int m = 0; m < 4; m++)
#pragma unroll
      for (int j = 0; j < 4; j++) li[m][j] = Lb[r0e + m * 16 + j];
    const int myh = wr >> 6;  // waves 0,1 -> half 0; waves 2,3 -> half 1
#pragma unroll
    for (int h = 0; h < 2; ++h) {
      if (myh == h) {
#pragma unroll
        for (int m = 0; m < 4; m++)
#pragma unroll
          for (int n = 0; n < 4; n++)
#pragma unroll
            for (int j = 0; j < 4; j++) {
              const int R = (wr & 63) + m * 16 + (lane >> 4) * 4 + j;  // 0..63
              const int Cc = wc + n * 16 + lr;                         // 0..127
              *(float*)(lds + R * 512 + ((Cc * 4) ^ ((R & 7) << 4))) =
                  acc[m][n][j] * li[m][j];
            }
      }
      __syncthreads();
      // read back float4 chunks; chunk (row, sl) holds cols sl*4..+3
      float* Ch = C + (size_t)(brow + h * 64) * ldc + bcol;
#pragma unroll
      for (int i = 0; i < 8; i++) {
        const int id = tid + i * 256;
        const int row = id >> 5, sl = id & 31;
        float4 vv = *(const float4*)(lds + row * 512 +
                                     ((sl * 16) ^ ((row & 7) << 4)));
        *(float4*)(Ch + (size_t)row * ldc + sl * 4) = vv;
      }
      __syncthreads();
    }
  } else {
    // bf16 path: round-trip through LDS (reuse 32KB) for ushort8 stores.
    const bool isV = (EPI == 0) && (bcol >= 1536);
    const bool isQ = (EPI == 0) && (bcol < 768);
    float bv[4];
    if (EPI == 0) {
#pragma unroll
      for (int n = 0; n < 4; n++) bv[n] = bias[bcol + wc + n * 16 + lr];
    }
    float rs[4][4];  // per-(m,j) row partial sums (EPI 1)
    if (EPI == 1) {
#pragma unroll
      for (int m = 0; m < 4; m++)
#pragma unroll
        for (int j = 0; j < 4; j++) rs[m][j] = 0.f;
    }
    // write acc -> LDS tile [128][128] bf16, slot ^= (row&15)
#pragma unroll
    for (int m = 0; m < 4; m++)
#pragma unroll
      for (int n = 0; n < 4; n++)
#pragma unroll
        for (int j = 0; j < 4; j++) {
          float v = acc[m][n][j];
          if (EPI == 0) {
            v += bv[n];
            if (isQ) v *= scale;
          }
          if (EPI == 1) {
            v = exp2f(v * 1.4426950408889634f);  // exp(s), no max needed
            rs[m][j] += v;
          }
          const int R = wr + (lane >> 4) * 4 + m * 16 + j;  // local row
          const int Cc = wc + n * 16 + lr;                  // local col
          const int row_ = isV ? Cc : R;
          const int col_ = isV ? R : Cc;
          *(unsigned short*)(lds + row_ * 256 +
                             ((col_ * 2) ^ ((row_ & 15) << 4))) = f2b(v);
        }
    if (EPI == 1) {
      // reduce rs across the 16 col-lanes (this wave's 64-col half)
#pragma unroll
      for (int m = 0; m < 4; m++)
#pragma unroll
        for (int j = 0; j < 4; j++) {
          float s = rs[m][j];
          s += __shfl_xor(s, 1);
          s += __shfl_xor(s, 2);
          s += __shfl_xor(s, 4);
          s += __shfl_xor(s, 8);
          rs[m][j] = s;
        }
      if (lr == 0) {
        float* Lp = Lpart + ((size_t)bz * 2048 + brow + wr +
                             (lane >> 4) * 4) * 32 + (bcol >> 7) * 2 + (wv & 1);
#pragma unroll
        for (int m = 0; m < 4; m++)
#pragma unroll
          for (int j = 0; j < 4; j++) Lp[(size_t)(m * 16 + j) * 32] = rs[m][j];
      }
    }
    __syncthreads();
    // read back rows, 16B chunks; chunk (row, sl) holds cols sl*8..+7
    if (isV) {
      const int b = brow >> 11;        // batch (BM=128 never straddles)
      const int l0 = brow & 2047;
      const int e0 = bcol - 1536;
      unsigned short* dst = vt + ((size_t)b * 768 + e0) * 2048 + l0;
#pragma unroll
      for (int i = 0; i < 8; i++) {
        const int id = tid + i * 256;
        const int row = id >> 4, sl = id & 15;
        ushort8 vv = *(const ushort8*)(lds + row * 256 +
                                       ((sl * 16) ^ ((row & 15) << 4)));
        *(ushort8*)(dst + (size_t)row * 2048 + sl * 8) = vv;
      }
    } else {
      unsigned short* C = (unsigned short*)Cv + (size_t)bz * sC +
                          (size_t)brow * ldc + bcol;
#pragma unroll
      for (int i = 0; i < 8; i++) {
        const int id = tid + i * 256;
        const int row = id >> 4, sl = id & 15;
        ushort8 vv = *(const ushort8*)(lds + row * 256 +
                                       ((sl * 16) ^ ((row & 15) << 4)));
        *(ushort8*)(C + (size_t)row * ldc + sl * 8) = vv;
      }
    }
  }
}

// ---------------- Lpart[rows][32] -> Linv[rows] = 1/sum ---------------------
__global__ __launch_bounds__(256) void sum_l(const float* __restrict__ Lpart,
                                             float* __restrict__ Linv, int nrows) {
  int r = blockIdx.x * blockDim.x + threadIdx.x;
  if (r >= nrows) return;
  const float4* p = (const float4*)(Lpart + (size_t)r * 32);
  float s = 0.f;
#pragma unroll
  for (int i = 0; i < 8; i++) {
    float4 v = p[i];
    s += (v.x + v.y) + (v.z + v.w);
  }
  Linv[r] = 1.0f / s;
}

// ---------------- host ------------------------------------------------------
extern "C" void kernel_launch(void* const* d_in, const int* in_sizes, int n_in,
                              void* d_out, int out_size, void* d_ws, size_t ws_size,
                              hipStream_t stream) {
  const float* x = (const float*)d_in[0];
  const float* W = (const float*)d_in[1];
  const float* bias = (const float*)d_in[2];
  float* out = (float*)d_out;
  char* ws = (char*)d_ws;

  unsigned short* xb = (unsigned short*)(ws);
  unsigned short* wb = (unsigned short*)(ws + 25165824);
  unsigned short* qkv = (unsigned short*)(ws + 28704768);
  unsigned short* vt = (unsigned short*)(ws + 104202240);
  unsigned short* S = (unsigned short*)(ws + 129368064);
  // Lpart/Linv reuse the xb region (xb is dead after the QKV GEMM):
  float* Lpart = (float*)(ws);                 // 16384*32*4 = 2 MB
  float* Linv = (float*)(ws + 2097152);        // 16384*4 = 64 KB
  const float scale = 0.03608439182435161f;    // 768^-0.5

  cvt_all<<<14016, 256, 0, stream>>>(x, W, xb, wb);
  // QKV = x @ W^T + b : M=16384 N=2304 K=768; Q scaled; V written to vt^T
  gemm128<0><<<dim3(18, 128, 1), 256, 0, stream>>>(
      xb, 768, 0, wb, 768, 0, qkv, 2304, 0, bias, scale, vt,
      nullptr, nullptr, 768);

  bool batched = ws_size >= (129368064UL + 67108864UL);
  if (batched) {
    // P~ = exp(Q @ K^T) per batch (scale folded into Q): M=N=2048 K=768
    gemm128<1><<<dim3(16, 16, 8), 256, 0, stream>>>(
        qkv, 2304, 2048L * 2304, qkv + 768, 2304, 2048L * 2304,
        S, 2048, 2048L * 2048, nullptr, 1.f, nullptr, Lpart, nullptr, 768);
    sum_l<<<64, 256, 0, stream>>>(Lpart, Linv, 16384);
    // out = (P~ @ V) * (1/l) : M=2048 N=768 K=2048
    gemm128<2><<<dim3(6, 16, 8), 256, 0, stream>>>(
        S, 2048, 2048L * 2048, vt, 2048, 768L * 2048,
        out, 768, 2048L * 768, nullptr, 1.f, nullptr, nullptr, Linv, 2048);
  } else {
    for (int b = 0; b < 8; b++) {
      const unsigned short* qb = qkv + (size_t)b * 2048 * 2304;
      gemm128<1><<<dim3(16, 16, 1), 256, 0, stream>>>(
          qb, 2304, 0, qb + 768, 2304, 0, S, 2048, 0, nullptr, 1.f, nullptr,
          Lpart, nullptr, 768);
      sum_l<<<8, 256, 0, stream>>>(Lpart, Linv, 2048);
      gemm128<2><<<dim3(6, 16, 1), 256, 0, stream>>>(
          S, 2048, 0, vt + (size_t)b * 768 * 2048, 2048, 0,
          out + (size_t)b * 2048 * 768, 768, 0, nullptr, 1.f, nullptr,
          nullptr, Linv, 2048);
    }
  }
}